// Round 2
// baseline (822.396 us; speedup 1.0000x reference)
//
#include <hip/hip_runtime.h>

#define T_SEQ 2048
#define BATCH 2
#define DMODEL 2048
#define NQH 32
#define NKVH 16
#define HD 128

typedef _Float16 f16;
typedef _Float16 f16x8 __attribute__((ext_vector_type(8)));
typedef _Float16 f16x4 __attribute__((ext_vector_type(4)));
typedef _Float16 f16x2 __attribute__((ext_vector_type(2)));
typedef float f32x4 __attribute__((ext_vector_type(4)));

typedef const __attribute__((address_space(1))) void* gptr_t;
typedef __attribute__((address_space(3))) void* sptr_t;
#define GLDS16(g, l) __builtin_amdgcn_global_load_lds((gptr_t)(g), (sptr_t)(l), 16, 0, 0)

// ---------------- elementwise f32 -> f16 convert (vectorized) ----------------
__global__ void k_convert_f16(const float* __restrict__ in, f16* __restrict__ out, int n8) {
  int i = blockIdx.x * blockDim.x + threadIdx.x;
  int stride = gridDim.x * blockDim.x;
  for (; i < n8; i += stride) {
    const float4* p = (const float4*)(in) + (size_t)i * 2;
    float4 a = p[0], b = p[1];
    f16x8 v;
    v[0]=(f16)a.x; v[1]=(f16)a.y; v[2]=(f16)a.z; v[3]=(f16)a.w;
    v[4]=(f16)b.x; v[5]=(f16)b.y; v[6]=(f16)b.z; v[7]=(f16)b.w;
    *((f16x8*)out + i) = v;
  }
}

// ---------------- tiled transpose + convert: W (K,N) f32 -> WT (N,K) f16 ----
__global__ __launch_bounds__(256) void k_transpose_f16(const float* __restrict__ W,
                                                       f16* __restrict__ WT, int K, int N) {
  __shared__ float tile[32][33];
  int n0 = blockIdx.x * 32, k0 = blockIdx.y * 32;
  int tx = threadIdx.x & 31;
  int ty0 = threadIdx.x >> 5;  // 0..7
  #pragma unroll
  for (int i = 0; i < 4; ++i) {
    int ty = ty0 + i * 8;
    tile[ty][tx] = W[(size_t)(k0 + ty) * N + n0 + tx];
  }
  __syncthreads();
  #pragma unroll
  for (int i = 0; i < 4; ++i) {
    int ty = ty0 + i * 8;
    WT[(size_t)(n0 + ty) * K + k0 + tx] = (f16)tile[tx][ty];
  }
}

// ---------------- GEMM: C(M,N) = A(M,K) @ B(K,N), B given transposed (N,K) --
// 128x128 tile, BK=32, 4 waves (2x2 of 64x64), mfma 16x16x32 f16 (m97 structure)
// OM: 0 = f32 C, 1 = f16 C, 2 = f16 transposed-per-head VT[b][h16][d][t]
template<int OM>
__global__ __launch_bounds__(256) void k_gemm(const f16* __restrict__ A,
                                              const f16* __restrict__ BT,
                                              void* __restrict__ Cv,
                                              int M, int N, int K) {
  __shared__ f16 Al[128 * 32];
  __shared__ f16 Bl[128 * 32];
  const int tid = threadIdx.x;
  const int lane = tid & 63;
  const int w = tid >> 6;
  const int wr = w >> 1, wc = w & 1;
  const int m0 = blockIdx.y * 128, n0 = blockIdx.x * 128;
  const int lr = lane & 15, lg = lane >> 4;
  f32x4 acc[4][4] = {};
  for (int kk = 0; kk < K; kk += 32) {
    #pragma unroll
    for (int q = 0; q < 2; ++q) {
      int idx = q * 256 + tid;
      GLDS16(A + (size_t)(m0 + (idx >> 2)) * K + kk + (idx & 3) * 8, &Al[(q * 256 + w * 64) * 8]);
      GLDS16(BT + (size_t)(n0 + (idx >> 2)) * K + kk + (idx & 3) * 8, &Bl[(q * 256 + w * 64) * 8]);
    }
    __syncthreads();
    f16x8 af[4], bf[4];
    #pragma unroll
    for (int i = 0; i < 4; ++i) af[i] = *(const f16x8*)&Al[(wr * 64 + i * 16 + lr) * 32 + lg * 8];
    #pragma unroll
    for (int j = 0; j < 4; ++j) bf[j] = *(const f16x8*)&Bl[(wc * 64 + j * 16 + lr) * 32 + lg * 8];
    #pragma unroll
    for (int i = 0; i < 4; ++i)
      #pragma unroll
      for (int j = 0; j < 4; ++j)
        acc[i][j] = __builtin_amdgcn_mfma_f32_16x16x32_f16(af[i], bf[j], acc[i][j], 0, 0, 0);
    __syncthreads();
  }
  #pragma unroll
  for (int i = 0; i < 4; ++i)
    #pragma unroll
    for (int j = 0; j < 4; ++j) {
      int r0 = m0 + wr * 64 + i * 16 + lg * 4;
      int c  = n0 + wc * 64 + j * 16 + lr;
      if (OM == 2) {
        int bb = r0 >> 11, t0 = r0 & (T_SEQ - 1);
        f16x4 zv;
        #pragma unroll
        for (int r = 0; r < 4; ++r) zv[r] = (f16)acc[i][j][r];
        *(f16x4*)((f16*)Cv + ((size_t)(bb * NKVH + (c >> 7)) * 128 + (c & 127)) * T_SEQ + t0) = zv;
      } else {
        #pragma unroll
        for (int r = 0; r < 4; ++r) {
          float v = acc[i][j][r];
          if (OM == 1) ((f16*)Cv)[(size_t)(r0 + r) * N + c] = (f16)v;
          else         ((float*)Cv)[(size_t)(r0 + r) * N + c] = v;
        }
      }
    }
}

// ---------------- RoPE interleaved, in-place on f16 (Q or K) ----------------
__global__ void k_rope(f16* __restrict__ X, const float* __restrict__ cosb,
                       const float* __restrict__ sinb, int nheads) {
  int total = BATCH * T_SEQ * nheads * 64;
  int stride = gridDim.x * blockDim.x;
  for (int i = blockIdx.x * blockDim.x + threadIdx.x; i < total; i += stride) {
    int j = i & 63;
    int tmp = i >> 6;
    int h = tmp % nheads;
    int row = tmp / nheads;          // b*T + t
    int t = row & (T_SEQ - 1);
    float c = cosb[t * 64 + j], s = sinb[t * 64 + j];
    f16x2* p = (f16x2*)(X + (size_t)row * nheads * HD + h * HD + 2 * j);
    f16x2 v = *p;
    float x1 = (float)v[0], x2 = (float)v[1];
    f16x2 o;
    o[0] = (f16)(x1 * c - x2 * s);
    o[1] = (f16)(x1 * s + x2 * c);
    *p = o;
  }
}

// ---------------- lambda = sigmoid(x @ Wlam), full fp32 ---------------------
__global__ __launch_bounds__(256) void k_lambda(const float* __restrict__ x,
                                                const float* __restrict__ Wlam,
                                                float* __restrict__ lam) {
  int row = blockIdx.x;
  const float* xr = x + (size_t)row * DMODEL;
  float acc[16];
  #pragma unroll
  for (int h = 0; h < 16; ++h) acc[h] = 0.f;
  for (int e = threadIdx.x; e < DMODEL; e += 256) {
    float xv = xr[e];
    const float4* wp = (const float4*)(Wlam + e * 16);
    #pragma unroll
    for (int g = 0; g < 4; ++g) {
      float4 wv = wp[g];
      acc[g * 4 + 0] += xv * wv.x; acc[g * 4 + 1] += xv * wv.y;
      acc[g * 4 + 2] += xv * wv.z; acc[g * 4 + 3] += xv * wv.w;
    }
  }
  #pragma unroll
  for (int h = 0; h < 16; ++h)
    for (int off = 32; off > 0; off >>= 1)
      acc[h] += __shfl_down(acc[h], off);
  __shared__ float part[4][16];
  int lane = threadIdx.x & 63, w = threadIdx.x >> 6;
  if (lane == 0) {
    #pragma unroll
    for (int h = 0; h < 16; ++h) part[w][h] = acc[h];
  }
  __syncthreads();
  if (threadIdx.x < 16) {
    float s = part[0][threadIdx.x] + part[1][threadIdx.x] + part[2][threadIdx.x] + part[3][threadIdx.x];
    lam[row * 16 + threadIdx.x] = 1.f / (1.f + __expf(-s));
  }
}

// ---------------- causal flash attention v2 ---------------------------------
// 256 threads (4 waves), 128 q-rows/block (32/wave), KV tile 64.
// K staged [64][128] f16 swizzled (slot^=row&7, 16B slots); VT staged [128][64]
// swizzled likewise. All fragment reads are ds_read_b128.
__global__ __launch_bounds__(256) void k_attn2(const f16* __restrict__ Q,
                                               const f16* __restrict__ K,
                                               const f16* __restrict__ VT,
                                               f16* __restrict__ O) {
  __shared__ f16 Kl[64 * 128];       // 16 KB, row s: 16 slots of 16B, swizzled
  __shared__ f16 Vl[128 * 64];       // 16 KB, row d: 8 slots of 16B, swizzled
  __shared__ f16 Pl[4][32][72];      // 18 KB, per-wave P, stride 144B (16B-aligned)
  const int tid = threadIdx.x;
  const int lane = tid & 63;
  const int w = tid >> 6;
  const int lr = lane & 15, lg = lane >> 4;
  const int qb = blockIdx.x * 128;
  const int bh = blockIdx.y;
  const int b = bh >> 5, h = bh & 31;
  const int hkv = h >> 1;
  const int qw = qb + w * 32;
  const f16* Kg  = K  + (size_t)b * T_SEQ * (NKVH * HD) + hkv * HD;
  const f16* VTg = VT + (size_t)(b * NKVH + hkv) * HD * T_SEQ;
  const float sc = 0.08838834764831845f;  // 1/sqrt(128)

  // Q fragments: qf[m][c] = Q[qw + m*16 + lr][c*32 + lg*8 ..]
  f16x8 qf[2][4];
  #pragma unroll
  for (int m = 0; m < 2; ++m) {
    const f16* qp = Q + (size_t)(b * T_SEQ + qw + m * 16 + lr) * (NQH * HD) + h * HD + lg * 8;
    #pragma unroll
    for (int c = 0; c < 4; ++c) qf[m][c] = *(const f16x8*)(qp + c * 32);
  }
  f32x4 o[2][8] = {};
  float mi[2][4], li[2][4];
  #pragma unroll
  for (int m = 0; m < 2; ++m)
    #pragma unroll
    for (int r = 0; r < 4; ++r) { mi[m][r] = -1e30f; li[m][r] = 0.f; }

  const int smax = qb + 128;
  for (int s0 = 0; s0 < smax; s0 += 64) {
    // ---- stage K tile: 64 rows x 16 slots; source slot pre-swizzled ----
    #pragma unroll
    for (int qq = 0; qq < 4; ++qq) {
      int idx = qq * 256 + tid;
      int r = idx >> 4, g = idx & 15;
      GLDS16(Kg + (size_t)(s0 + r) * (NKVH * HD) + (g ^ (r & 7)) * 8, &Kl[idx * 8]);
    }
    // ---- stage VT tile: 128 rows(d) x 8 slots; source slot pre-swizzled ----
    #pragma unroll
    for (int qq = 0; qq < 4; ++qq) {
      int idx = qq * 256 + tid;
      int d = idx >> 3, g = idx & 7;
      GLDS16(VTg + (size_t)d * T_SEQ + s0 + (g ^ (d & 7)) * 8, &Vl[idx * 8]);
    }
    __syncthreads();

    if (s0 < qw + 32) {  // wave-uniform: tile intersects this wave's causal span
      // ---- S = Q K^T : sf[m][nb], rows qw+m*16+.., cols s0+nb*16+lr ----
      f32x4 sf[2][4] = {};
      #pragma unroll
      for (int c = 0; c < 4; ++c) {
        f16x8 kf[4];
        #pragma unroll
        for (int nb = 0; nb < 4; ++nb)
          kf[nb] = *(const f16x8*)&Kl[(((nb * 16 + lr) * 16) + ((c * 4 + lg) ^ (lr & 7))) * 8];
        #pragma unroll
        for (int m = 0; m < 2; ++m)
          #pragma unroll
          for (int nb = 0; nb < 4; ++nb)
            sf[m][nb] = __builtin_amdgcn_mfma_f32_16x16x32_f16(qf[m][c], kf[nb], sf[m][nb], 0, 0, 0);
      }
      // ---- online softmax ----
      const bool domask = (s0 + 64 > qw);
      #pragma unroll
      for (int m = 0; m < 2; ++m)
        #pragma unroll
        for (int rr = 0; rr < 4; ++rr) {
          int qrow = qw + m * 16 + lg * 4 + rr;
          float v[4];
          #pragma unroll
          for (int nb = 0; nb < 4; ++nb) {
            v[nb] = sf[m][nb][rr] * sc;
            if (domask && (s0 + nb * 16 + lr > qrow)) v[nb] = -1e30f;
          }
          float pm = fmaxf(fmaxf(v[0], v[1]), fmaxf(v[2], v[3]));
          #pragma unroll
          for (int off = 1; off < 16; off <<= 1) pm = fmaxf(pm, __shfl_xor(pm, off));
          float mnew = fmaxf(mi[m][rr], pm);
          float a = __expf(mi[m][rr] - mnew);
          float rs = 0.f;
          #pragma unroll
          for (int nb = 0; nb < 4; ++nb) {
            float p = __expf(v[nb] - mnew);
            rs += p;
            Pl[w][m * 16 + lg * 4 + rr][nb * 16 + lr] = (f16)p;
          }
          #pragma unroll
          for (int off = 1; off < 16; off <<= 1) rs += __shfl_xor(rs, off);
          li[m][rr] = a * li[m][rr] + rs;
          mi[m][rr] = mnew;
          #pragma unroll
          for (int j = 0; j < 8; ++j) o[m][j][rr] *= a;
        }
      // ---- PV: o[m][j] += P[m] x V, k = 64 in two 32-chunks ----
      #pragma unroll
      for (int ks = 0; ks < 2; ++ks) {
        f16x8 pa[2];
        #pragma unroll
        for (int m = 0; m < 2; ++m)
          pa[m] = *(const f16x8*)&Pl[w][m * 16 + lr][ks * 32 + lg * 8];
        f16x8 vb[8];
        #pragma unroll
        for (int j = 0; j < 8; ++j)
          vb[j] = *(const f16x8*)&Vl[(((j * 16 + lr) * 8) + ((ks * 4 + lg) ^ (lr & 7))) * 8];
        #pragma unroll
        for (int m = 0; m < 2; ++m)
          #pragma unroll
          for (int j = 0; j < 8; ++j)
            o[m][j] = __builtin_amdgcn_mfma_f32_16x16x32_f16(pa[m], vb[j], o[m][j], 0, 0, 0);
      }
    }
    __syncthreads();
  }
  // ---- epilogue ----
  #pragma unroll
  for (int m = 0; m < 2; ++m)
    #pragma unroll
    for (int j = 0; j < 8; ++j)
      #pragma unroll
      for (int rr = 0; rr < 4; ++rr) {
        float v = o[m][j][rr] / li[m][rr];
        O[(size_t)(b * T_SEQ + qw + m * 16 + lg * 4 + rr) * (NQH * HD) + h * HD + j * 16 + lr] = (f16)v;
      }
}

// ---------------- differential combine: Z = attn_even - lam * attn_odd ------
__global__ void k_combine(const f16* __restrict__ attn, const float* __restrict__ lam,
                          f16* __restrict__ Z) {
  int idx = blockIdx.x * blockDim.x + threadIdx.x;
  int d4 = idx & 31;
  int tmp = idx >> 5;
  int h = tmp & 15;
  int row = tmp >> 4;
  if (row >= BATCH * T_SEQ) return;
  float lv = lam[row * 16 + h];
  f16x4 a1 = *(const f16x4*)(attn + (size_t)row * 4096 + (2 * h) * 128 + d4 * 4);
  f16x4 a2 = *(const f16x4*)(attn + (size_t)row * 4096 + (2 * h + 1) * 128 + d4 * 4);
  f16x4 z;
  #pragma unroll
  for (int e = 0; e < 4; ++e) z[e] = (f16)((float)a1[e] - lv * (float)a2[e]);
  *(f16x4*)(Z + (size_t)row * 2048 + h * 128 + d4 * 4) = z;
}

extern "C" void kernel_launch(void* const* d_in, const int* in_sizes, int n_in,
                              void* d_out, int out_size, void* d_ws, size_t ws_size,
                              hipStream_t stream) {
  const float* x    = (const float*)d_in[0];
  const float* cosb = (const float*)d_in[1];
  const float* sinb = (const float*)d_in[2];
  const float* Wq   = (const float*)d_in[3];
  const float* Wk   = (const float*)d_in[4];
  const float* Wv   = (const float*)d_in[5];
  const float* Wo   = (const float*)d_in[6];
  const float* Wlam = (const float*)d_in[7];

  char* ws = (char*)d_ws;
  f16*  xh  = (f16*)(ws);                    // x f16           16 MB
  f16*  WqT = (f16*)(ws + 16777216);         // Wq^T (4096,2048) 16 MB
  f16*  WkT = (f16*)(ws + 33554432);         //  8 MB
  f16*  WvT = (f16*)(ws + 41943040);         //  8 MB
  f16*  WoT = (f16*)(ws + 50331648);         //  8 MB
  f16*  Qh  = (f16*)(ws + 58720256);         // (4096,4096) 32 MB
  f16*  Kh  = (f16*)(ws + 92274688);         // (4096,2048) 16 MB
  f16*  VTg = (f16*)(ws + 109051904);        // VT (32 heads,128,2048) 16 MB
  f16*  At  = (f16*)(ws + 125829120);        // attn (4096,4096) 32 MB
  f16*  Zh  = (f16*)(ws + 159383552);        // (4096,2048) 16 MB
  float* lam = (float*)(ws + 176160768);     // (4096,16)

  k_convert_f16<<<2048, 256, 0, stream>>>(x, xh, BATCH * T_SEQ * DMODEL / 8);
  k_transpose_f16<<<dim3(4096 / 32, 2048 / 32), 256, 0, stream>>>(Wq, WqT, DMODEL, 4096);
  k_transpose_f16<<<dim3(2048 / 32, 2048 / 32), 256, 0, stream>>>(Wk, WkT, DMODEL, 2048);
  k_transpose_f16<<<dim3(2048 / 32, 2048 / 32), 256, 0, stream>>>(Wv, WvT, DMODEL, 2048);
  k_transpose_f16<<<dim3(2048 / 32, 2048 / 32), 256, 0, stream>>>(Wo, WoT, 2048, 2048);

  k_gemm<1><<<dim3(4096 / 128, 4096 / 128), 256, 0, stream>>>(xh, WqT, Qh, 4096, 4096, 2048);
  k_gemm<1><<<dim3(2048 / 128, 4096 / 128), 256, 0, stream>>>(xh, WkT, Kh, 4096, 2048, 2048);
  k_gemm<2><<<dim3(2048 / 128, 4096 / 128), 256, 0, stream>>>(xh, WvT, VTg, 4096, 2048, 2048);

  k_rope<<<2048, 256, 0, stream>>>(Qh, cosb, sinb, NQH);
  k_rope<<<2048, 256, 0, stream>>>(Kh, cosb, sinb, NKVH);
  k_lambda<<<4096, 256, 0, stream>>>(x, Wlam, lam);

  k_attn2<<<dim3(T_SEQ / 128, BATCH * NQH), 256, 0, stream>>>(Qh, Kh, VTg, At);

  k_combine<<<(BATCH * T_SEQ * 16 * 32) / 256, 256, 0, stream>>>(At, lam, Zh);
  k_gemm<0><<<dim3(2048 / 128, 4096 / 128), 256, 0, stream>>>(Zh, WoT, d_out, 4096, 2048, 2048);
}

// Round 3
// 689.939 us; speedup vs baseline: 1.1920x; 1.1920x over previous
//
#include <hip/hip_runtime.h>

#define T_SEQ 2048
#define BATCH 2
#define DMODEL 2048
#define NQH 32
#define NKVH 16
#define HD 128

typedef _Float16 f16;
typedef _Float16 f16x8 __attribute__((ext_vector_type(8)));
typedef _Float16 f16x4 __attribute__((ext_vector_type(4)));
typedef _Float16 f16x2 __attribute__((ext_vector_type(2)));
typedef float f32x4 __attribute__((ext_vector_type(4)));

typedef const __attribute__((address_space(1))) void* gptr_t;
typedef __attribute__((address_space(3))) void* sptr_t;
#define GLDS16(g, l) __builtin_amdgcn_global_load_lds((gptr_t)(g), (sptr_t)(l), 16, 0, 0)

// ---------------- elementwise f32 -> f16 convert (vectorized) ----------------
__global__ void k_convert_f16(const float* __restrict__ in, f16* __restrict__ out, int n8) {
  int i = blockIdx.x * blockDim.x + threadIdx.x;
  int stride = gridDim.x * blockDim.x;
  for (; i < n8; i += stride) {
    const float4* p = (const float4*)(in) + (size_t)i * 2;
    float4 a = p[0], b = p[1];
    f16x8 v;
    v[0]=(f16)a.x; v[1]=(f16)a.y; v[2]=(f16)a.z; v[3]=(f16)a.w;
    v[4]=(f16)b.x; v[5]=(f16)b.y; v[6]=(f16)b.z; v[7]=(f16)b.w;
    *((f16x8*)out + i) = v;
  }
}

// ---------------- tiled transpose + convert: W (K,N) f32 -> WT (N,K) f16 ----
__global__ __launch_bounds__(256) void k_transpose_f16(const float* __restrict__ W,
                                                       f16* __restrict__ WT, int K, int N) {
  __shared__ float tile[32][33];
  int n0 = blockIdx.x * 32, k0 = blockIdx.y * 32;
  int tx = threadIdx.x & 31;
  int ty0 = threadIdx.x >> 5;  // 0..7
  #pragma unroll
  for (int i = 0; i < 4; ++i) {
    int ty = ty0 + i * 8;
    tile[ty][tx] = W[(size_t)(k0 + ty) * N + n0 + tx];
  }
  __syncthreads();
  #pragma unroll
  for (int i = 0; i < 4; ++i) {
    int ty = ty0 + i * 8;
    WT[(size_t)(n0 + ty) * K + k0 + tx] = (f16)tile[tx][ty];
  }
}

// ---------------- GEMM: C(M,N) = A(M,K) @ B(K,N), B given transposed (N,K) --
// 128x128 tile, BK=32, 4 waves (2x2 of 64x64), mfma 16x16x32 f16 (m97 structure)
// OM: 0 = f32 C, 1 = f16 C, 2 = f16 transposed-per-head VT[b][h16][d][t]
template<int OM>
__global__ __launch_bounds__(256) void k_gemm(const f16* __restrict__ A,
                                              const f16* __restrict__ BT,
                                              void* __restrict__ Cv,
                                              int M, int N, int K) {
  __shared__ f16 Al[128 * 32];
  __shared__ f16 Bl[128 * 32];
  const int tid = threadIdx.x;
  const int lane = tid & 63;
  const int w = tid >> 6;
  const int wr = w >> 1, wc = w & 1;
  const int m0 = blockIdx.y * 128, n0 = blockIdx.x * 128;
  const int lr = lane & 15, lg = lane >> 4;
  f32x4 acc[4][4] = {};
  for (int kk = 0; kk < K; kk += 32) {
    #pragma unroll
    for (int q = 0; q < 2; ++q) {
      int idx = q * 256 + tid;
      GLDS16(A + (size_t)(m0 + (idx >> 2)) * K + kk + (idx & 3) * 8, &Al[(q * 256 + w * 64) * 8]);
      GLDS16(BT + (size_t)(n0 + (idx >> 2)) * K + kk + (idx & 3) * 8, &Bl[(q * 256 + w * 64) * 8]);
    }
    __syncthreads();
    f16x8 af[4], bf[4];
    #pragma unroll
    for (int i = 0; i < 4; ++i) af[i] = *(const f16x8*)&Al[(wr * 64 + i * 16 + lr) * 32 + lg * 8];
    #pragma unroll
    for (int j = 0; j < 4; ++j) bf[j] = *(const f16x8*)&Bl[(wc * 64 + j * 16 + lr) * 32 + lg * 8];
    #pragma unroll
    for (int i = 0; i < 4; ++i)
      #pragma unroll
      for (int j = 0; j < 4; ++j)
        acc[i][j] = __builtin_amdgcn_mfma_f32_16x16x32_f16(af[i], bf[j], acc[i][j], 0, 0, 0);
    __syncthreads();
  }
  #pragma unroll
  for (int i = 0; i < 4; ++i)
    #pragma unroll
    for (int j = 0; j < 4; ++j) {
      int r0 = m0 + wr * 64 + i * 16 + lg * 4;
      int c  = n0 + wc * 64 + j * 16 + lr;
      if (OM == 2) {
        int bb = r0 >> 11, t0 = r0 & (T_SEQ - 1);
        f16x4 zv;
        #pragma unroll
        for (int r = 0; r < 4; ++r) zv[r] = (f16)acc[i][j][r];
        *(f16x4*)((f16*)Cv + ((size_t)(bb * NKVH + (c >> 7)) * 128 + (c & 127)) * T_SEQ + t0) = zv;
      } else {
        #pragma unroll
        for (int r = 0; r < 4; ++r) {
          float v = acc[i][j][r];
          if (OM == 1) ((f16*)Cv)[(size_t)(r0 + r) * N + c] = (f16)v;
          else         ((float*)Cv)[(size_t)(r0 + r) * N + c] = v;
        }
      }
    }
}

// ---------------- RoPE interleaved, in-place on f16 (Q or K) ----------------
__global__ void k_rope(f16* __restrict__ X, const float* __restrict__ cosb,
                       const float* __restrict__ sinb, int nheads) {
  int total = BATCH * T_SEQ * nheads * 64;
  int stride = gridDim.x * blockDim.x;
  for (int i = blockIdx.x * blockDim.x + threadIdx.x; i < total; i += stride) {
    int j = i & 63;
    int tmp = i >> 6;
    int h = tmp % nheads;
    int row = tmp / nheads;          // b*T + t
    int t = row & (T_SEQ - 1);
    float c = cosb[t * 64 + j], s = sinb[t * 64 + j];
    f16x2* p = (f16x2*)(X + (size_t)row * nheads * HD + h * HD + 2 * j);
    f16x2 v = *p;
    float x1 = (float)v[0], x2 = (float)v[1];
    f16x2 o;
    o[0] = (f16)(x1 * c - x2 * s);
    o[1] = (f16)(x1 * s + x2 * c);
    *p = o;
  }
}

// ---------------- lambda = sigmoid(x @ Wlam), full fp32 ---------------------
__global__ __launch_bounds__(256) void k_lambda(const float* __restrict__ x,
                                                const float* __restrict__ Wlam,
                                                float* __restrict__ lam) {
  int row = blockIdx.x;
  const float* xr = x + (size_t)row * DMODEL;
  float acc[16];
  #pragma unroll
  for (int h = 0; h < 16; ++h) acc[h] = 0.f;
  for (int e = threadIdx.x; e < DMODEL; e += 256) {
    float xv = xr[e];
    const float4* wp = (const float4*)(Wlam + e * 16);
    #pragma unroll
    for (int g = 0; g < 4; ++g) {
      float4 wv = wp[g];
      acc[g * 4 + 0] += xv * wv.x; acc[g * 4 + 1] += xv * wv.y;
      acc[g * 4 + 2] += xv * wv.z; acc[g * 4 + 3] += xv * wv.w;
    }
  }
  #pragma unroll
  for (int h = 0; h < 16; ++h)
    for (int off = 32; off > 0; off >>= 1)
      acc[h] += __shfl_down(acc[h], off);
  __shared__ float part[4][16];
  int lane = threadIdx.x & 63, w = threadIdx.x >> 6;
  if (lane == 0) {
    #pragma unroll
    for (int h = 0; h < 16; ++h) part[w][h] = acc[h];
  }
  __syncthreads();
  if (threadIdx.x < 16) {
    float s = part[0][threadIdx.x] + part[1][threadIdx.x] + part[2][threadIdx.x] + part[3][threadIdx.x];
    lam[row * 16 + threadIdx.x] = 1.f / (1.f + __expf(-s));
  }
}

// ---------------- causal flash attention v3 ---------------------------------
// 256 threads (4 waves), two paired 128-row q-tiles per block (uniform work),
// KV tile 64, K/V double-buffered (stage t+1 issued before compute t),
// per-wave P LDS [16][66] with split-m PV. LDS total = 74 KB -> 2 blocks/CU.
__global__ __launch_bounds__(256) void k_attn3(const f16* __restrict__ Q,
                                               const f16* __restrict__ K,
                                               const f16* __restrict__ VT,
                                               f16* __restrict__ O) {
  __shared__ f16 Kl[2][64 * 128];    // 2 x 16 KB
  __shared__ f16 Vl[2][128 * 64];    // 2 x 16 KB
  __shared__ f16 Pl[4][16][66];      // 8.25 KB, per-wave P (one m at a time)
  const int tid = threadIdx.x;
  const int lane = tid & 63;
  const int w = tid >> 6;
  const int lr = lane & 15, lg = lane >> 4;
  const int bh = blockIdx.y;
  const int b = bh >> 5, h = bh & 31;
  const int hkv = h >> 1;
  const f16* Kg  = K  + (size_t)b * T_SEQ * (NKVH * HD) + hkv * HD;
  const f16* VTg = VT + (size_t)(b * NKVH + hkv) * HD * T_SEQ;
  const float sc = 0.08838834764831845f;  // 1/sqrt(128)

  #pragma unroll 1
  for (int half = 0; half < 2; ++half) {
    const int qt = half ? (15 - (int)blockIdx.x) : (int)blockIdx.x;
    const int qb = qt * 128;
    const int qw = qb + w * 32;
    // Q fragments
    f16x8 qf[2][4];
    #pragma unroll
    for (int m = 0; m < 2; ++m) {
      const f16* qp = Q + (size_t)(b * T_SEQ + qw + m * 16 + lr) * (NQH * HD) + h * HD + lg * 8;
      #pragma unroll
      for (int c = 0; c < 4; ++c) qf[m][c] = *(const f16x8*)(qp + c * 32);
    }
    f32x4 o[2][8] = {};
    float mi[2][4], li[2][4];
    #pragma unroll
    for (int m = 0; m < 2; ++m)
      #pragma unroll
      for (int r = 0; r < 4; ++r) { mi[m][r] = -1e30f; li[m][r] = 0.f; }

    const int nt = (qb + 128) / 64;
    // prologue stage tile 0 -> buf 0
    {
      #pragma unroll
      for (int qq = 0; qq < 4; ++qq) {
        int idx = qq * 256 + tid;
        int r = idx >> 4, g = idx & 15;
        GLDS16(Kg + (size_t)r * (NKVH * HD) + (g ^ (r & 7)) * 8, &Kl[0][idx * 8]);
      }
      #pragma unroll
      for (int qq = 0; qq < 4; ++qq) {
        int idx = qq * 256 + tid;
        int d = idx >> 3, g = idx & 7;
        GLDS16(VTg + (size_t)d * T_SEQ + (g ^ (d & 7)) * 8, &Vl[0][idx * 8]);
      }
    }
    __syncthreads();

    for (int t = 0; t < nt; ++t) {
      const int buf = t & 1;
      const int s0 = t * 64;
      // ---- issue next tile's staging into the other buffer ----
      if (t + 1 < nt) {
        const int s1 = s0 + 64;
        #pragma unroll
        for (int qq = 0; qq < 4; ++qq) {
          int idx = qq * 256 + tid;
          int r = idx >> 4, g = idx & 15;
          GLDS16(Kg + (size_t)(s1 + r) * (NKVH * HD) + (g ^ (r & 7)) * 8, &Kl[buf ^ 1][idx * 8]);
        }
        #pragma unroll
        for (int qq = 0; qq < 4; ++qq) {
          int idx = qq * 256 + tid;
          int d = idx >> 3, g = idx & 7;
          GLDS16(VTg + (size_t)d * T_SEQ + s1 + (g ^ (d & 7)) * 8, &Vl[buf ^ 1][idx * 8]);
        }
      }
      // ---- compute current tile ----
      if (s0 < qw + 32) {
        // QK^T for both m
        f32x4 sf[2][4] = {};
        #pragma unroll
        for (int c = 0; c < 4; ++c) {
          f16x8 kf[4];
          #pragma unroll
          for (int nb = 0; nb < 4; ++nb)
            kf[nb] = *(const f16x8*)&Kl[buf][(((nb * 16 + lr) * 16) + ((c * 4 + lg) ^ (lr & 7))) * 8];
          #pragma unroll
          for (int m = 0; m < 2; ++m)
            #pragma unroll
            for (int nb = 0; nb < 4; ++nb)
              sf[m][nb] = __builtin_amdgcn_mfma_f32_16x16x32_f16(qf[m][c], kf[nb], sf[m][nb], 0, 0, 0);
        }
        const bool domask = (s0 + 64 > qw);
        #pragma unroll
        for (int m = 0; m < 2; ++m) {
          // softmax for this m, write P rows [0..15]
          #pragma unroll
          for (int rr = 0; rr < 4; ++rr) {
            int qrow = qw + m * 16 + lg * 4 + rr;
            float v[4];
            #pragma unroll
            for (int nb = 0; nb < 4; ++nb) {
              v[nb] = sf[m][nb][rr] * sc;
              if (domask && (s0 + nb * 16 + lr > qrow)) v[nb] = -1e30f;
            }
            float pm = fmaxf(fmaxf(v[0], v[1]), fmaxf(v[2], v[3]));
            #pragma unroll
            for (int off = 1; off < 16; off <<= 1) pm = fmaxf(pm, __shfl_xor(pm, off));
            float mnew = fmaxf(mi[m][rr], pm);
            float a = __expf(mi[m][rr] - mnew);
            float rs = 0.f;
            #pragma unroll
            for (int nb = 0; nb < 4; ++nb) {
              float p = __expf(v[nb] - mnew);
              rs += p;
              Pl[w][lg * 4 + rr][nb * 16 + lr] = (f16)p;
            }
            #pragma unroll
            for (int off = 1; off < 16; off <<= 1) rs += __shfl_xor(rs, off);
            li[m][rr] = a * li[m][rr] + rs;
            mi[m][rr] = mnew;
            #pragma unroll
            for (int j = 0; j < 8; ++j) o[m][j][rr] *= a;
          }
          // PV for this m (DS in-order per wave: reads precede next m's writes)
          #pragma unroll
          for (int ks = 0; ks < 2; ++ks) {
            f16x8 pa = *(const f16x8*)&Pl[w][lr][ks * 32 + lg * 8];
            #pragma unroll
            for (int j = 0; j < 8; ++j) {
              f16x8 vbj = *(const f16x8*)&Vl[buf][(((j * 16 + lr) * 8) + ((ks * 4 + lg) ^ (lr & 7))) * 8];
              o[m][j] = __builtin_amdgcn_mfma_f32_16x16x32_f16(pa, vbj, o[m][j], 0, 0, 0);
            }
          }
        }
      }
      __syncthreads();  // drains next-tile staging; all waves done with buf
    }
    // ---- epilogue ----
    #pragma unroll
    for (int m = 0; m < 2; ++m)
      #pragma unroll
      for (int j = 0; j < 8; ++j)
        #pragma unroll
        for (int rr = 0; rr < 4; ++rr) {
          float v = o[m][j][rr] / li[m][rr];
          O[(size_t)(b * T_SEQ + qw + m * 16 + lg * 4 + rr) * (NQH * HD) + h * HD + j * 16 + lr] = (f16)v;
        }
  }
}

// ---------------- differential combine: Z = attn_even - lam * attn_odd ------
__global__ void k_combine(const f16* __restrict__ attn, const float* __restrict__ lam,
                          f16* __restrict__ Z) {
  int idx = blockIdx.x * blockDim.x + threadIdx.x;
  int d4 = idx & 31;
  int tmp = idx >> 5;
  int h = tmp & 15;
  int row = tmp >> 4;
  if (row >= BATCH * T_SEQ) return;
  float lv = lam[row * 16 + h];
  f16x4 a1 = *(const f16x4*)(attn + (size_t)row * 4096 + (2 * h) * 128 + d4 * 4);
  f16x4 a2 = *(const f16x4*)(attn + (size_t)row * 4096 + (2 * h + 1) * 128 + d4 * 4);
  f16x4 z;
  #pragma unroll
  for (int e = 0; e < 4; ++e) z[e] = (f16)((float)a1[e] - lv * (float)a2[e]);
  *(f16x4*)(Z + (size_t)row * 2048 + h * 128 + d4 * 4) = z;
}

extern "C" void kernel_launch(void* const* d_in, const int* in_sizes, int n_in,
                              void* d_out, int out_size, void* d_ws, size_t ws_size,
                              hipStream_t stream) {
  const float* x    = (const float*)d_in[0];
  const float* cosb = (const float*)d_in[1];
  const float* sinb = (const float*)d_in[2];
  const float* Wq   = (const float*)d_in[3];
  const float* Wk   = (const float*)d_in[4];
  const float* Wv   = (const float*)d_in[5];
  const float* Wo   = (const float*)d_in[6];
  const float* Wlam = (const float*)d_in[7];

  char* ws = (char*)d_ws;
  f16*  xh  = (f16*)(ws);                    // x f16           16 MB
  f16*  WqT = (f16*)(ws + 16777216);         // Wq^T (4096,2048) 16 MB
  f16*  WkT = (f16*)(ws + 33554432);         //  8 MB
  f16*  WvT = (f16*)(ws + 41943040);         //  8 MB
  f16*  WoT = (f16*)(ws + 50331648);         //  8 MB
  f16*  Qh  = (f16*)(ws + 58720256);         // (4096,4096) 32 MB
  f16*  Kh  = (f16*)(ws + 92274688);         // (4096,2048) 16 MB
  f16*  VTg = (f16*)(ws + 109051904);        // VT (32 heads,128,2048) 16 MB
  f16*  At  = (f16*)(ws + 125829120);        // attn (4096,4096) 32 MB
  f16*  Zh  = (f16*)(ws + 159383552);        // (4096,2048) 16 MB
  float* lam = (float*)(ws + 176160768);     // (4096,16)

  k_convert_f16<<<2048, 256, 0, stream>>>(x, xh, BATCH * T_SEQ * DMODEL / 8);
  k_transpose_f16<<<dim3(4096 / 32, 2048 / 32), 256, 0, stream>>>(Wq, WqT, DMODEL, 4096);
  k_transpose_f16<<<dim3(2048 / 32, 2048 / 32), 256, 0, stream>>>(Wk, WkT, DMODEL, 2048);
  k_transpose_f16<<<dim3(2048 / 32, 2048 / 32), 256, 0, stream>>>(Wv, WvT, DMODEL, 2048);
  k_transpose_f16<<<dim3(2048 / 32, 2048 / 32), 256, 0, stream>>>(Wo, WoT, 2048, 2048);

  k_gemm<1><<<dim3(4096 / 128, 4096 / 128), 256, 0, stream>>>(xh, WqT, Qh, 4096, 4096, 2048);
  k_gemm<1><<<dim3(2048 / 128, 4096 / 128), 256, 0, stream>>>(xh, WkT, Kh, 4096, 2048, 2048);
  k_gemm<2><<<dim3(2048 / 128, 4096 / 128), 256, 0, stream>>>(xh, WvT, VTg, 4096, 2048, 2048);

  k_rope<<<2048, 256, 0, stream>>>(Qh, cosb, sinb, NQH);
  k_rope<<<2048, 256, 0, stream>>>(Kh, cosb, sinb, NKVH);
  k_lambda<<<4096, 256, 0, stream>>>(x, Wlam, lam);

  k_attn3<<<dim3(8, BATCH * NQH), 256, 0, stream>>>(Qh, Kh, VTg, At);

  k_combine<<<(BATCH * T_SEQ * 16 * 32) / 256, 256, 0, stream>>>(At, lam, Zh);
  k_gemm<0><<<dim3(2048 / 128, 4096 / 128), 256, 0, stream>>>(Zh, WoT, d_out, 4096, 2048, 2048);
}

// Round 4
// 522.271 us; speedup vs baseline: 1.5747x; 1.3210x over previous
//
#include <hip/hip_runtime.h>

#define T_SEQ 2048
#define BATCH 2
#define DMODEL 2048
#define NQH 32
#define NKVH 16
#define HD 128

typedef _Float16 f16;
typedef _Float16 f16x8 __attribute__((ext_vector_type(8)));
typedef _Float16 f16x4 __attribute__((ext_vector_type(4)));
typedef _Float16 f16x2 __attribute__((ext_vector_type(2)));
typedef float f32x4 __attribute__((ext_vector_type(4)));

typedef const __attribute__((address_space(1))) void* gptr_t;
typedef __attribute__((address_space(3))) void* sptr_t;
#define GLDS16(g, l) __builtin_amdgcn_global_load_lds((gptr_t)(g), (sptr_t)(l), 16, 0, 0)

// ---------------- elementwise f32 -> f16 convert (vectorized) ----------------
__global__ void k_convert_f16(const float* __restrict__ in, f16* __restrict__ out, int n8) {
  int i = blockIdx.x * blockDim.x + threadIdx.x;
  int stride = gridDim.x * blockDim.x;
  for (; i < n8; i += stride) {
    const float4* p = (const float4*)(in) + (size_t)i * 2;
    float4 a = p[0], b = p[1];
    f16x8 v;
    v[0]=(f16)a.x; v[1]=(f16)a.y; v[2]=(f16)a.z; v[3]=(f16)a.w;
    v[4]=(f16)b.x; v[5]=(f16)b.y; v[6]=(f16)b.z; v[7]=(f16)b.w;
    *((f16x8*)out + i) = v;
  }
}

// ---------------- tiled transpose + convert: W (K,N) f32 -> WT (N,K) f16 ----
__global__ __launch_bounds__(256) void k_transpose_f16(const float* __restrict__ W,
                                                       f16* __restrict__ WT, int K, int N) {
  __shared__ float tile[32][33];
  int n0 = blockIdx.x * 32, k0 = blockIdx.y * 32;
  int tx = threadIdx.x & 31;
  int ty0 = threadIdx.x >> 5;  // 0..7
  #pragma unroll
  for (int i = 0; i < 4; ++i) {
    int ty = ty0 + i * 8;
    tile[ty][tx] = W[(size_t)(k0 + ty) * N + n0 + tx];
  }
  __syncthreads();
  #pragma unroll
  for (int i = 0; i < 4; ++i) {
    int ty = ty0 + i * 8;
    WT[(size_t)(n0 + ty) * K + k0 + tx] = (f16)tile[tx][ty];
  }
}

// ---------------- GEMM: C(M,N) = A(M,K) @ B(K,N), B given transposed (N,K) --
// 128x128 tile, BK=32, 4 waves (2x2 of 64x64), mfma 16x16x32 f16 (m97 structure)
// OM: 0 = f32 C, 1 = f16 C, 2 = f16 transposed-per-head VT[b][h16][d][t]
template<int OM>
__global__ __launch_bounds__(256) void k_gemm(const f16* __restrict__ A,
                                              const f16* __restrict__ BT,
                                              void* __restrict__ Cv,
                                              int M, int N, int K) {
  __shared__ f16 Al[128 * 32];
  __shared__ f16 Bl[128 * 32];
  const int tid = threadIdx.x;
  const int lane = tid & 63;
  const int w = tid >> 6;
  const int wr = w >> 1, wc = w & 1;
  const int m0 = blockIdx.y * 128, n0 = blockIdx.x * 128;
  const int lr = lane & 15, lg = lane >> 4;
  f32x4 acc[4][4] = {};
  for (int kk = 0; kk < K; kk += 32) {
    #pragma unroll
    for (int q = 0; q < 2; ++q) {
      int idx = q * 256 + tid;
      GLDS16(A + (size_t)(m0 + (idx >> 2)) * K + kk + (idx & 3) * 8, &Al[(q * 256 + w * 64) * 8]);
      GLDS16(BT + (size_t)(n0 + (idx >> 2)) * K + kk + (idx & 3) * 8, &Bl[(q * 256 + w * 64) * 8]);
    }
    __syncthreads();
    f16x8 af[4], bf[4];
    #pragma unroll
    for (int i = 0; i < 4; ++i) af[i] = *(const f16x8*)&Al[(wr * 64 + i * 16 + lr) * 32 + lg * 8];
    #pragma unroll
    for (int j = 0; j < 4; ++j) bf[j] = *(const f16x8*)&Bl[(wc * 64 + j * 16 + lr) * 32 + lg * 8];
    #pragma unroll
    for (int i = 0; i < 4; ++i)
      #pragma unroll
      for (int j = 0; j < 4; ++j)
        acc[i][j] = __builtin_amdgcn_mfma_f32_16x16x32_f16(af[i], bf[j], acc[i][j], 0, 0, 0);
    __syncthreads();
  }
  #pragma unroll
  for (int i = 0; i < 4; ++i)
    #pragma unroll
    for (int j = 0; j < 4; ++j) {
      int r0 = m0 + wr * 64 + i * 16 + lg * 4;
      int c  = n0 + wc * 64 + j * 16 + lr;
      if (OM == 2) {
        int bb = r0 >> 11, t0 = r0 & (T_SEQ - 1);
        f16x4 zv;
        #pragma unroll
        for (int r = 0; r < 4; ++r) zv[r] = (f16)acc[i][j][r];
        *(f16x4*)((f16*)Cv + ((size_t)(bb * NKVH + (c >> 7)) * 128 + (c & 127)) * T_SEQ + t0) = zv;
      } else {
        #pragma unroll
        for (int r = 0; r < 4; ++r) {
          float v = acc[i][j][r];
          if (OM == 1) ((f16*)Cv)[(size_t)(r0 + r) * N + c] = (f16)v;
          else         ((float*)Cv)[(size_t)(r0 + r) * N + c] = v;
        }
      }
    }
}

// ---------------- RoPE interleaved, in-place on f16 (Q or K) ----------------
__global__ void k_rope(f16* __restrict__ X, const float* __restrict__ cosb,
                       const float* __restrict__ sinb, int nheads) {
  int total = BATCH * T_SEQ * nheads * 64;
  int stride = gridDim.x * blockDim.x;
  for (int i = blockIdx.x * blockDim.x + threadIdx.x; i < total; i += stride) {
    int j = i & 63;
    int tmp = i >> 6;
    int h = tmp % nheads;
    int row = tmp / nheads;          // b*T + t
    int t = row & (T_SEQ - 1);
    float c = cosb[t * 64 + j], s = sinb[t * 64 + j];
    f16x2* p = (f16x2*)(X + (size_t)row * nheads * HD + h * HD + 2 * j);
    f16x2 v = *p;
    float x1 = (float)v[0], x2 = (float)v[1];
    f16x2 o;
    o[0] = (f16)(x1 * c - x2 * s);
    o[1] = (f16)(x1 * s + x2 * c);
    *p = o;
  }
}

// ---------------- lambda = sigmoid(x @ Wlam), full fp32 ---------------------
__global__ __launch_bounds__(256) void k_lambda(const float* __restrict__ x,
                                                const float* __restrict__ Wlam,
                                                float* __restrict__ lam) {
  int row = blockIdx.x;
  const float* xr = x + (size_t)row * DMODEL;
  float acc[16];
  #pragma unroll
  for (int h = 0; h < 16; ++h) acc[h] = 0.f;
  for (int e = threadIdx.x; e < DMODEL; e += 256) {
    float xv = xr[e];
    const float4* wp = (const float4*)(Wlam + e * 16);
    #pragma unroll
    for (int g = 0; g < 4; ++g) {
      float4 wv = wp[g];
      acc[g * 4 + 0] += xv * wv.x; acc[g * 4 + 1] += xv * wv.y;
      acc[g * 4 + 2] += xv * wv.z; acc[g * 4 + 3] += xv * wv.w;
    }
  }
  #pragma unroll
  for (int h = 0; h < 16; ++h)
    for (int off = 32; off > 0; off >>= 1)
      acc[h] += __shfl_down(acc[h], off);
  __shared__ float part[4][16];
  int lane = threadIdx.x & 63, w = threadIdx.x >> 6;
  if (lane == 0) {
    #pragma unroll
    for (int h = 0; h < 16; ++h) part[w][h] = acc[h];
  }
  __syncthreads();
  if (threadIdx.x < 16) {
    float s = part[0][threadIdx.x] + part[1][threadIdx.x] + part[2][threadIdx.x] + part[3][threadIdx.x];
    lam[row * 16 + threadIdx.x] = 1.f / (1.f + __expf(-s));
  }
}

// ---------------- causal flash attention v4 ---------------------------------
// 256 threads (4 waves), 64 q-rows/block (16/wave), KV tile 64 single-buffered.
// Swapped QK^T: mfma(K,Q) puts a full P-row per lane (q-row = lane&15) ->
// softmax is in-register + 4 shfl. P via small per-wave LDS (ks-half reuse).
// LDS = 16K + 16K + 5K = 37.9 KB, VGPR capped 128 -> 4 blocks/CU, 4 waves/SIMD.
// Grid: flat 1024 = (b,hkv) groups x 2 qheads x 16 paired q-tiles, XCD-pinned.
__global__ __launch_bounds__(256, 4) void k_attn4(const f16* __restrict__ Q,
                                                  const f16* __restrict__ K,
                                                  const f16* __restrict__ VT,
                                                  f16* __restrict__ O) {
  __shared__ f16 Kl[64 * 128];     // 16 KB: row s (64), 16 slots of 16B, swizzled
  __shared__ f16 Vl[128 * 64];     // 16 KB: row d (128), 8 slots of 16B, swizzled
  __shared__ f16 Pl[4][16][40];    // 5 KB: per-wave P half-tile (32 cols + pad)
  const int tid = threadIdx.x;
  const int lane = tid & 63;
  const int w = tid >> 6;
  const int lr = lane & 15, lg = lane >> 4;
  // ---- XCD-pinned work decode: all 32 blocks of one (b,hkv) on one XCD ----
  const int flat = blockIdx.x;           // 0..1023
  const int xcd = flat & 7;
  const int work = xcd * 128 + (flat >> 3);
  const int grp = work >> 5;             // b*16 + hkv
  const int within = work & 31;
  const int b = grp >> 4, hkv = grp & 15;
  const int h = hkv * 2 + (within >> 4);
  const int bx = within & 15;
  const f16* Kg  = K  + (size_t)b * T_SEQ * (NKVH * HD) + hkv * HD;
  const f16* VTg = VT + (size_t)(b * NKVH + hkv) * HD * T_SEQ;
  const float sc = 0.08838834764831845f;  // 1/sqrt(128)

  #pragma unroll 1
  for (int half = 0; half < 2; ++half) {
    const int qt = half ? (31 - bx) : bx;
    const int qb = qt * 64;
    const int qw = qb + w * 16;          // this wave's 16 q-rows
    const int qrow = qw + lr;            // this lane's q-row
    // Q fragments (B-operand): qf[c] = Q[qrow][c*32 + lg*8 ..]
    f16x8 qf[4];
    {
      const f16* qp = Q + (size_t)(b * T_SEQ + qrow) * (NQH * HD) + h * HD + lg * 8;
      #pragma unroll
      for (int c = 0; c < 4; ++c) qf[c] = *(const f16x8*)(qp + c * 32);
    }
    f32x4 o[8] = {};
    float mi = -1e30f, li = 0.f;

    const int nt = qt + 1;
    #pragma unroll 1
    for (int t = 0; t < nt; ++t) {
      const int s0 = t * 64;
      // ---- stage K [64][128] + V [128][64], swizzled source slots ----
      #pragma unroll
      for (int qq = 0; qq < 4; ++qq) {
        int idx = qq * 256 + tid;
        int r = idx >> 4, g = idx & 15;
        GLDS16(Kg + (size_t)(s0 + r) * (NKVH * HD) + (g ^ (r & 7)) * 8, &Kl[idx * 8]);
      }
      #pragma unroll
      for (int qq = 0; qq < 4; ++qq) {
        int idx = qq * 256 + tid;
        int d = idx >> 3, g = idx & 7;
        GLDS16(VTg + (size_t)d * T_SEQ + s0 + (g ^ (d & 7)) * 8, &Vl[idx * 8]);
      }
      __syncthreads();  // vmcnt(0) drain + all waves ready

      // ---- S^T = K Q^T : lane holds S[kv = s0+nb*16+lg*4+rr][q = qrow] ----
      f32x4 sf[4] = {};
      #pragma unroll
      for (int c = 0; c < 4; ++c) {
        #pragma unroll
        for (int nb = 0; nb < 4; ++nb) {
          f16x8 kf = *(const f16x8*)&Kl[(((nb * 16 + lr) * 16) + ((c * 4 + lg) ^ (lr & 7))) * 8];
          sf[nb] = __builtin_amdgcn_mfma_f32_16x16x32_f16(kf, qf[c], sf[nb], 0, 0, 0);
        }
      }
      // ---- in-register softmax over the lane's 16 S-values ----
      float v[16];
      #pragma unroll
      for (int nb = 0; nb < 4; ++nb)
        #pragma unroll
        for (int rr = 0; rr < 4; ++rr) {
          float x = sf[nb][rr] * sc;
          int kv = s0 + nb * 16 + lg * 4 + rr;
          v[nb * 4 + rr] = (kv > qrow) ? -1e30f : x;
        }
      float pm = v[0];
      #pragma unroll
      for (int i = 1; i < 16; ++i) pm = fmaxf(pm, v[i]);
      pm = fmaxf(pm, __shfl_xor(pm, 16));
      pm = fmaxf(pm, __shfl_xor(pm, 32));
      float mnew = fmaxf(mi, pm);
      float a = __expf(mi - mnew);
      mi = mnew;
      float rs = 0.f;
      #pragma unroll
      for (int i = 0; i < 16; ++i) { float p = __expf(v[i] - mnew); v[i] = p; rs += p; }
      rs += __shfl_xor(rs, 16);
      rs += __shfl_xor(rs, 32);
      li = a * li + rs;
      float ab[4];
      #pragma unroll
      for (int rr = 0; rr < 4; ++rr) ab[rr] = __shfl(a, lg * 4 + rr);
      #pragma unroll
      for (int j = 0; j < 8; ++j)
        #pragma unroll
        for (int rr = 0; rr < 4; ++rr) o[j][rr] *= ab[rr];
      // ---- PV in two ks-halves; P half-buffer reused (wave-local DS order) ----
      #pragma unroll
      for (int ks = 0; ks < 2; ++ks) {
        #pragma unroll
        for (int nb2 = 0; nb2 < 2; ++nb2) {
          int nb = ks * 2 + nb2;
          f16x4 pk;
          #pragma unroll
          for (int rr = 0; rr < 4; ++rr) pk[rr] = (f16)v[nb * 4 + rr];
          *(f16x4*)&Pl[w][lr][nb2 * 16 + lg * 4] = pk;
        }
        f16x8 pa = *(const f16x8*)&Pl[w][lr][lg * 8];
        #pragma unroll
        for (int j = 0; j < 8; ++j) {
          f16x8 vbj = *(const f16x8*)&Vl[(((j * 16 + lr) * 8) + ((ks * 4 + lg) ^ (lr & 7))) * 8];
          o[j] = __builtin_amdgcn_mfma_f32_16x16x32_f16(pa, vbj, o[j], 0, 0, 0);
        }
      }
      __syncthreads();  // all waves done with Kl/Vl before next stage
    }
    // ---- epilogue: rows lg*4+rr, cols j*16+lr ----
    float lib[4];
    #pragma unroll
    for (int rr = 0; rr < 4; ++rr) lib[rr] = 1.f / __shfl(li, lg * 4 + rr);
    #pragma unroll
    for (int j = 0; j < 8; ++j)
      #pragma unroll
      for (int rr = 0; rr < 4; ++rr) {
        float vv = o[j][rr] * lib[rr];
        O[(size_t)(b * T_SEQ + qw + lg * 4 + rr) * (NQH * HD) + h * HD + j * 16 + lr] = (f16)vv;
      }
  }
}

// ---------------- differential combine: Z = attn_even - lam * attn_odd ------
__global__ void k_combine(const f16* __restrict__ attn, const float* __restrict__ lam,
                          f16* __restrict__ Z) {
  int idx = blockIdx.x * blockDim.x + threadIdx.x;
  int d4 = idx & 31;
  int tmp = idx >> 5;
  int h = tmp & 15;
  int row = tmp >> 4;
  if (row >= BATCH * T_SEQ) return;
  float lv = lam[row * 16 + h];
  f16x4 a1 = *(const f16x4*)(attn + (size_t)row * 4096 + (2 * h) * 128 + d4 * 4);
  f16x4 a2 = *(const f16x4*)(attn + (size_t)row * 4096 + (2 * h + 1) * 128 + d4 * 4);
  f16x4 z;
  #pragma unroll
  for (int e = 0; e < 4; ++e) z[e] = (f16)((float)a1[e] - lv * (float)a2[e]);
  *(f16x4*)(Z + (size_t)row * 2048 + h * 128 + d4 * 4) = z;
}

extern "C" void kernel_launch(void* const* d_in, const int* in_sizes, int n_in,
                              void* d_out, int out_size, void* d_ws, size_t ws_size,
                              hipStream_t stream) {
  const float* x    = (const float*)d_in[0];
  const float* cosb = (const float*)d_in[1];
  const float* sinb = (const float*)d_in[2];
  const float* Wq   = (const float*)d_in[3];
  const float* Wk   = (const float*)d_in[4];
  const float* Wv   = (const float*)d_in[5];
  const float* Wo   = (const float*)d_in[6];
  const float* Wlam = (const float*)d_in[7];

  char* ws = (char*)d_ws;
  f16*  xh  = (f16*)(ws);                    // x f16           16 MB
  f16*  WqT = (f16*)(ws + 16777216);         // Wq^T (4096,2048) 16 MB
  f16*  WkT = (f16*)(ws + 33554432);         //  8 MB
  f16*  WvT = (f16*)(ws + 41943040);         //  8 MB
  f16*  WoT = (f16*)(ws + 50331648);         //  8 MB
  f16*  Qh  = (f16*)(ws + 58720256);         // (4096,4096) 32 MB
  f16*  Kh  = (f16*)(ws + 92274688);         // (4096,2048) 16 MB
  f16*  VTg = (f16*)(ws + 109051904);        // VT (32 heads,128,2048) 16 MB
  f16*  At  = (f16*)(ws + 125829120);        // attn (4096,4096) 32 MB
  f16*  Zh  = (f16*)(ws + 159383552);        // (4096,2048) 16 MB
  float* lam = (float*)(ws + 176160768);     // (4096,16)

  k_convert_f16<<<2048, 256, 0, stream>>>(x, xh, BATCH * T_SEQ * DMODEL / 8);
  k_transpose_f16<<<dim3(4096 / 32, 2048 / 32), 256, 0, stream>>>(Wq, WqT, DMODEL, 4096);
  k_transpose_f16<<<dim3(2048 / 32, 2048 / 32), 256, 0, stream>>>(Wk, WkT, DMODEL, 2048);
  k_transpose_f16<<<dim3(2048 / 32, 2048 / 32), 256, 0, stream>>>(Wv, WvT, DMODEL, 2048);
  k_transpose_f16<<<dim3(2048 / 32, 2048 / 32), 256, 0, stream>>>(Wo, WoT, 2048, 2048);

  k_gemm<1><<<dim3(4096 / 128, 4096 / 128), 256, 0, stream>>>(xh, WqT, Qh, 4096, 4096, 2048);
  k_gemm<1><<<dim3(2048 / 128, 4096 / 128), 256, 0, stream>>>(xh, WkT, Kh, 4096, 2048, 2048);
  k_gemm<2><<<dim3(2048 / 128, 4096 / 128), 256, 0, stream>>>(xh, WvT, VTg, 4096, 2048, 2048);

  k_rope<<<2048, 256, 0, stream>>>(Qh, cosb, sinb, NQH);
  k_rope<<<2048, 256, 0, stream>>>(Kh, cosb, sinb, NKVH);
  k_lambda<<<4096, 256, 0, stream>>>(x, Wlam, lam);

  k_attn4<<<1024, 256, 0, stream>>>(Qh, Kh, VTg, At);

  k_combine<<<(BATCH * T_SEQ * 16 * 32) / 256, 256, 0, stream>>>(At, lam, Zh);
  k_gemm<0><<<dim3(2048 / 128, 4096 / 128), 256, 0, stream>>>(Zh, WoT, d_out, 4096, 2048, 2048);
}

// Round 5
// 416.599 us; speedup vs baseline: 1.9741x; 1.2537x over previous
//
#include <hip/hip_runtime.h>

#define T_SEQ 2048
#define BATCH 2
#define DMODEL 2048
#define NQH 32
#define NKVH 16
#define HD 128

typedef _Float16 f16;
typedef _Float16 f16x8 __attribute__((ext_vector_type(8)));
typedef _Float16 f16x4 __attribute__((ext_vector_type(4)));
typedef _Float16 f16x2 __attribute__((ext_vector_type(2)));
typedef float f32x4 __attribute__((ext_vector_type(4)));

typedef const __attribute__((address_space(1))) void* gptr_t;
typedef __attribute__((address_space(3))) void* sptr_t;
#define GLDS16(g, l) __builtin_amdgcn_global_load_lds((gptr_t)(g), (sptr_t)(l), 16, 0, 0)

// ---------------- elementwise f32 -> f16 convert (vectorized) ----------------
__global__ void k_convert_f16(const float* __restrict__ in, f16* __restrict__ out, int n8) {
  int i = blockIdx.x * blockDim.x + threadIdx.x;
  int stride = gridDim.x * blockDim.x;
  for (; i < n8; i += stride) {
    const float4* p = (const float4*)(in) + (size_t)i * 2;
    float4 a = p[0], b = p[1];
    f16x8 v;
    v[0]=(f16)a.x; v[1]=(f16)a.y; v[2]=(f16)a.z; v[3]=(f16)a.w;
    v[4]=(f16)b.x; v[5]=(f16)b.y; v[6]=(f16)b.z; v[7]=(f16)b.w;
    *((f16x8*)out + i) = v;
  }
}

// ---------------- tiled transpose + convert: W (K,N) f32 -> WT (N,K) f16 ----
__global__ __launch_bounds__(256) void k_transpose_f16(const float* __restrict__ W,
                                                       f16* __restrict__ WT, int K, int N) {
  __shared__ float tile[32][33];
  int n0 = blockIdx.x * 32, k0 = blockIdx.y * 32;
  int tx = threadIdx.x & 31;
  int ty0 = threadIdx.x >> 5;  // 0..7
  #pragma unroll
  for (int i = 0; i < 4; ++i) {
    int ty = ty0 + i * 8;
    tile[ty][tx] = W[(size_t)(k0 + ty) * N + n0 + tx];
  }
  __syncthreads();
  #pragma unroll
  for (int i = 0; i < 4; ++i) {
    int ty = ty0 + i * 8;
    WT[(size_t)(n0 + ty) * K + k0 + tx] = (f16)tile[tx][ty];
  }
}

// ---------------- pipelined GEMM v2 ------------------------------------------
// C(M,N) = A(M,K) @ B(K,N), B given transposed (N,K). BK=64, 8 waves (WMxWN),
// double-buffered LDS, counted vmcnt(L) (prefetch spans barriers, never
// drained to 0 in-loop), raw s_barrier + sched_barrier fences.
// OM=0: f32 C.  OM=3: fused QKV epilogue (RoPE for Q/K, transposed store for V).
template<int BM, int BN, int WM, int WN, int OM>
__global__ __launch_bounds__(512, 2) void k_gemm2(const f16* __restrict__ A,
                                                  const f16* __restrict__ BT,
                                                  void* __restrict__ C0,
                                                  f16* __restrict__ Kh,
                                                  f16* __restrict__ VTg,
                                                  const float* __restrict__ cosb,
                                                  const float* __restrict__ sinb,
                                                  int M, int N, int K) {
  constexpr int MR = BM / WM / 16;       // M fragments per wave
  constexpr int NR = BN / WN / 16;       // N fragments per wave
  constexpr int ACH = BM / 64;           // A 16B-chunks per thread per stage
  constexpr int BCH = BN / 64;
  __shared__ alignas(16) f16 Al[2][BM * 64];
  __shared__ alignas(16) f16 Bl[2][BN * 64];
  const int tid = threadIdx.x;
  const int lane = tid & 63;
  const int w = tid >> 6;
  const int wr = w / WN, wc = w % WN;
  const int lr = lane & 15, lg = lane >> 4;
  // bijective XCD swizzle (grid % 8 == 0 for all our launches)
  const int nbx = N / BN;
  const int cpx = gridDim.x >> 3;
  const int wg = (blockIdx.x & 7) * cpx + (blockIdx.x >> 3);
  const int m0 = (wg / nbx) * BM, n0 = (wg % nbx) * BN;

  auto STAGE = [&](int buf, int kk) {
    #pragma unroll
    for (int q = 0; q < ACH; ++q) {
      int idx = q * 512 + tid;
      int r = idx >> 3, g = idx & 7;
      GLDS16(A + (size_t)(m0 + r) * K + kk + ((g ^ (r & 7)) * 8), &Al[buf][idx * 8]);
    }
    #pragma unroll
    for (int q = 0; q < BCH; ++q) {
      int idx = q * 512 + tid;
      int r = idx >> 3, g = idx & 7;
      GLDS16(BT + (size_t)(n0 + r) * K + kk + ((g ^ (r & 7)) * 8), &Bl[buf][idx * 8]);
    }
  };

  f32x4 acc[MR][NR] = {};
  STAGE(0, 0);
  const int nt = K / 64;
  #pragma unroll 2
  for (int t = 0; t < nt; ++t) {
    const int buf = t & 1;
    if (t + 1 < nt) {
      STAGE(buf ^ 1, (t + 1) * 64);
      __builtin_amdgcn_sched_barrier(0);
      if constexpr (ACH + BCH == 8) asm volatile("s_waitcnt vmcnt(8)" ::: "memory");
      else                          asm volatile("s_waitcnt vmcnt(6)" ::: "memory");
    } else {
      __builtin_amdgcn_sched_barrier(0);
      asm volatile("s_waitcnt vmcnt(0)" ::: "memory");
    }
    __builtin_amdgcn_s_barrier();          // current tile visible to all waves
    __builtin_amdgcn_sched_barrier(0);
    #pragma unroll
    for (int kh = 0; kh < 2; ++kh) {
      f16x8 af[MR], bf[NR];
      #pragma unroll
      for (int i = 0; i < MR; ++i) {
        int r = wr * (BM / WM) + i * 16 + lr;
        af[i] = *(const f16x8*)&Al[buf][r * 64 + (((kh * 4 + lg) ^ (r & 7)) * 8)];
      }
      #pragma unroll
      for (int j = 0; j < NR; ++j) {
        int r = wc * (BN / WN) + j * 16 + lr;
        bf[j] = *(const f16x8*)&Bl[buf][r * 64 + (((kh * 4 + lg) ^ (r & 7)) * 8)];
      }
      #pragma unroll
      for (int i = 0; i < MR; ++i)
        #pragma unroll
        for (int j = 0; j < NR; ++j)
          acc[i][j] = __builtin_amdgcn_mfma_f32_16x16x32_f16(af[i], bf[j], acc[i][j], 0, 0, 0);
    }
    __builtin_amdgcn_sched_barrier(0);
    __builtin_amdgcn_s_barrier();          // all waves done reading buf
    __builtin_amdgcn_sched_barrier(0);
  }

  // ---- epilogue ----
  const int mb = m0 + wr * (BM / WM);
  const int nb = n0 + wc * (BN / WN);
  if constexpr (OM == 0) {
    float* C = (float*)C0;
    #pragma unroll
    for (int i = 0; i < MR; ++i)
      #pragma unroll
      for (int j = 0; j < NR; ++j) {
        int r0 = mb + i * 16 + lg * 4;
        int c = nb + j * 16 + lr;
        #pragma unroll
        for (int r = 0; r < 4; ++r)
          C[(size_t)(r0 + r) * N + c] = acc[i][j][r];
      }
  } else {
    if (n0 < 6144) {  // Q (cols 0..4095) or K (4096..6143): apply RoPE, row-major f16
      f16* dst = (n0 < 4096) ? (f16*)C0 : Kh;
      const int ncols = (n0 < 4096) ? 4096 : 2048;
      const int coff = (n0 < 4096) ? 0 : 4096;
      #pragma unroll
      for (int i = 0; i < MR; ++i)
        #pragma unroll
        for (int j = 0; j < NR; ++j) {
          int c = nb + j * 16 + lr - coff;
          int jp = (c & 127) >> 1;
          bool odd = (c & 1);
          #pragma unroll
          for (int r = 0; r < 4; ++r) {
            int row = mb + i * 16 + lg * 4 + r;
            int t = row & (T_SEQ - 1);
            float v = acc[i][j][r];
            float pv = __shfl_xor(v, 1);   // partner column (c^1) value
            float cs = cosb[t * 64 + jp], sn = sinb[t * 64 + jp];
            float out = odd ? (pv * sn + v * cs) : (v * cs - pv * sn);
            dst[(size_t)row * ncols + c] = (f16)out;
          }
        }
    } else {          // V (cols 6144..8191): store transposed per head VT[b][h][d][t]
      #pragma unroll
      for (int i = 0; i < MR; ++i)
        #pragma unroll
        for (int j = 0; j < NR; ++j) {
          int c = nb + j * 16 + lr - 6144;
          int head = c >> 7, d = c & 127;
          int row0 = mb + i * 16 + lg * 4;
          int bb = row0 >> 11, t0 = row0 & (T_SEQ - 1);
          f16x4 zv;
          #pragma unroll
          for (int r = 0; r < 4; ++r) zv[r] = (f16)acc[i][j][r];
          *(f16x4*)(VTg + ((size_t)(bb * NKVH + head) * HD + d) * T_SEQ + t0) = zv;
        }
    }
  }
}

// ---------------- lambda = sigmoid(x @ Wlam), full fp32 ---------------------
__global__ __launch_bounds__(256) void k_lambda(const float* __restrict__ x,
                                                const float* __restrict__ Wlam,
                                                float* __restrict__ lam) {
  int row = blockIdx.x;
  const float* xr = x + (size_t)row * DMODEL;
  float acc[16];
  #pragma unroll
  for (int h = 0; h < 16; ++h) acc[h] = 0.f;
  for (int e = threadIdx.x; e < DMODEL; e += 256) {
    float xv = xr[e];
    const float4* wp = (const float4*)(Wlam + e * 16);
    #pragma unroll
    for (int g = 0; g < 4; ++g) {
      float4 wv = wp[g];
      acc[g * 4 + 0] += xv * wv.x; acc[g * 4 + 1] += xv * wv.y;
      acc[g * 4 + 2] += xv * wv.z; acc[g * 4 + 3] += xv * wv.w;
    }
  }
  #pragma unroll
  for (int h = 0; h < 16; ++h)
    for (int off = 32; off > 0; off >>= 1)
      acc[h] += __shfl_down(acc[h], off);
  __shared__ float part[4][16];
  int lane = threadIdx.x & 63, w = threadIdx.x >> 6;
  if (lane == 0) {
    #pragma unroll
    for (int h = 0; h < 16; ++h) part[w][h] = acc[h];
  }
  __syncthreads();
  if (threadIdx.x < 16) {
    float s = part[0][threadIdx.x] + part[1][threadIdx.x] + part[2][threadIdx.x] + part[3][threadIdx.x];
    lam[row * 16 + threadIdx.x] = 1.f / (1.f + __expf(-s));
  }
}

// ---------------- causal flash attention v4 (unchanged from round 4) --------
__global__ __launch_bounds__(256, 4) void k_attn4(const f16* __restrict__ Q,
                                                  const f16* __restrict__ K,
                                                  const f16* __restrict__ VT,
                                                  f16* __restrict__ O) {
  __shared__ f16 Kl[64 * 128];
  __shared__ f16 Vl[128 * 64];
  __shared__ f16 Pl[4][16][40];
  const int tid = threadIdx.x;
  const int lane = tid & 63;
  const int w = tid >> 6;
  const int lr = lane & 15, lg = lane >> 4;
  const int flat = blockIdx.x;
  const int xcd = flat & 7;
  const int work = xcd * 128 + (flat >> 3);
  const int grp = work >> 5;
  const int within = work & 31;
  const int b = grp >> 4, hkv = grp & 15;
  const int h = hkv * 2 + (within >> 4);
  const int bx = within & 15;
  const f16* Kg  = K  + (size_t)b * T_SEQ * (NKVH * HD) + hkv * HD;
  const f16* VTg = VT + (size_t)(b * NKVH + hkv) * HD * T_SEQ;
  const float sc = 0.08838834764831845f;

  #pragma unroll 1
  for (int half = 0; half < 2; ++half) {
    const int qt = half ? (31 - bx) : bx;
    const int qb = qt * 64;
    const int qw = qb + w * 16;
    const int qrow = qw + lr;
    f16x8 qf[4];
    {
      const f16* qp = Q + (size_t)(b * T_SEQ + qrow) * (NQH * HD) + h * HD + lg * 8;
      #pragma unroll
      for (int c = 0; c < 4; ++c) qf[c] = *(const f16x8*)(qp + c * 32);
    }
    f32x4 o[8] = {};
    float mi = -1e30f, li = 0.f;

    const int nt = qt + 1;
    #pragma unroll 1
    for (int t = 0; t < nt; ++t) {
      const int s0 = t * 64;
      #pragma unroll
      for (int qq = 0; qq < 4; ++qq) {
        int idx = qq * 256 + tid;
        int r = idx >> 4, g = idx & 15;
        GLDS16(Kg + (size_t)(s0 + r) * (NKVH * HD) + (g ^ (r & 7)) * 8, &Kl[idx * 8]);
      }
      #pragma unroll
      for (int qq = 0; qq < 4; ++qq) {
        int idx = qq * 256 + tid;
        int d = idx >> 3, g = idx & 7;
        GLDS16(VTg + (size_t)d * T_SEQ + s0 + (g ^ (d & 7)) * 8, &Vl[idx * 8]);
      }
      __syncthreads();

      f32x4 sf[4] = {};
      #pragma unroll
      for (int c = 0; c < 4; ++c) {
        #pragma unroll
        for (int nb = 0; nb < 4; ++nb) {
          f16x8 kf = *(const f16x8*)&Kl[(((nb * 16 + lr) * 16) + ((c * 4 + lg) ^ (lr & 7))) * 8];
          sf[nb] = __builtin_amdgcn_mfma_f32_16x16x32_f16(kf, qf[c], sf[nb], 0, 0, 0);
        }
      }
      float v[16];
      #pragma unroll
      for (int nb = 0; nb < 4; ++nb)
        #pragma unroll
        for (int rr = 0; rr < 4; ++rr) {
          float x = sf[nb][rr] * sc;
          int kv = s0 + nb * 16 + lg * 4 + rr;
          v[nb * 4 + rr] = (kv > qrow) ? -1e30f : x;
        }
      float pm = v[0];
      #pragma unroll
      for (int i = 1; i < 16; ++i) pm = fmaxf(pm, v[i]);
      pm = fmaxf(pm, __shfl_xor(pm, 16));
      pm = fmaxf(pm, __shfl_xor(pm, 32));
      float mnew = fmaxf(mi, pm);
      float a = __expf(mi - mnew);
      mi = mnew;
      float rs = 0.f;
      #pragma unroll
      for (int i = 0; i < 16; ++i) { float p = __expf(v[i] - mnew); v[i] = p; rs += p; }
      rs += __shfl_xor(rs, 16);
      rs += __shfl_xor(rs, 32);
      li = a * li + rs;
      float ab[4];
      #pragma unroll
      for (int rr = 0; rr < 4; ++rr) ab[rr] = __shfl(a, lg * 4 + rr);
      #pragma unroll
      for (int j = 0; j < 8; ++j)
        #pragma unroll
        for (int rr = 0; rr < 4; ++rr) o[j][rr] *= ab[rr];
      #pragma unroll
      for (int ks = 0; ks < 2; ++ks) {
        #pragma unroll
        for (int nb2 = 0; nb2 < 2; ++nb2) {
          int nb = ks * 2 + nb2;
          f16x4 pk;
          #pragma unroll
          for (int rr = 0; rr < 4; ++rr) pk[rr] = (f16)v[nb * 4 + rr];
          *(f16x4*)&Pl[w][lr][nb2 * 16 + lg * 4] = pk;
        }
        f16x8 pa = *(const f16x8*)&Pl[w][lr][lg * 8];
        #pragma unroll
        for (int j = 0; j < 8; ++j) {
          f16x8 vbj = *(const f16x8*)&Vl[(((j * 16 + lr) * 8) + ((ks * 4 + lg) ^ (lr & 7))) * 8];
          o[j] = __builtin_amdgcn_mfma_f32_16x16x32_f16(pa, vbj, o[j], 0, 0, 0);
        }
      }
      __syncthreads();
    }
    float lib[4];
    #pragma unroll
    for (int rr = 0; rr < 4; ++rr) lib[rr] = 1.f / __shfl(li, lg * 4 + rr);
    #pragma unroll
    for (int j = 0; j < 8; ++j)
      #pragma unroll
      for (int rr = 0; rr < 4; ++rr) {
        float vv = o[j][rr] * lib[rr];
        O[(size_t)(b * T_SEQ + qw + lg * 4 + rr) * (NQH * HD) + h * HD + j * 16 + lr] = (f16)vv;
      }
  }
}

// ---------------- differential combine: Z = attn_even - lam * attn_odd ------
__global__ void k_combine(const f16* __restrict__ attn, const float* __restrict__ lam,
                          f16* __restrict__ Z) {
  int idx = blockIdx.x * blockDim.x + threadIdx.x;
  int d4 = idx & 31;
  int tmp = idx >> 5;
  int h = tmp & 15;
  int row = tmp >> 4;
  if (row >= BATCH * T_SEQ) return;
  float lv = lam[row * 16 + h];
  f16x4 a1 = *(const f16x4*)(attn + (size_t)row * 4096 + (2 * h) * 128 + d4 * 4);
  f16x4 a2 = *(const f16x4*)(attn + (size_t)row * 4096 + (2 * h + 1) * 128 + d4 * 4);
  f16x4 z;
  #pragma unroll
  for (int e = 0; e < 4; ++e) z[e] = (f16)((float)a1[e] - lv * (float)a2[e]);
  *(f16x4*)(Z + (size_t)row * 2048 + h * 128 + d4 * 4) = z;
}

extern "C" void kernel_launch(void* const* d_in, const int* in_sizes, int n_in,
                              void* d_out, int out_size, void* d_ws, size_t ws_size,
                              hipStream_t stream) {
  const float* x    = (const float*)d_in[0];
  const float* cosb = (const float*)d_in[1];
  const float* sinb = (const float*)d_in[2];
  const float* Wq   = (const float*)d_in[3];
  const float* Wk   = (const float*)d_in[4];
  const float* Wv   = (const float*)d_in[5];
  const float* Wo   = (const float*)d_in[6];
  const float* Wlam = (const float*)d_in[7];

  char* ws = (char*)d_ws;
  f16*  xh     = (f16*)(ws);                      // 16 MB  x in f16
  f16*  WqkvT  = (f16*)(ws + 16777216);           // 32 MB  [Wq^T; Wk^T; Wv^T] (8192,2048)
  f16*  WoT    = (f16*)(ws + 50331648);           //  8 MB
  f16*  Qh     = (f16*)(ws + 58720256);           // 32 MB  (4096,4096) rope'd
  f16*  Kh     = (f16*)(ws + 92274688);           // 16 MB  (4096,2048) rope'd
  f16*  VTg    = (f16*)(ws + 109051904);          // 16 MB  (32 head-slices,128,2048)
  f16*  At     = (f16*)(ws + 125829120);          // 32 MB  attn out (4096,4096)
  f16*  Zh     = (f16*)(ws + 159383552);          // 16 MB  (4096,2048)
  float* lam   = (float*)(ws + 176160768);        // 256 KB (4096,16)

  k_convert_f16<<<2048, 256, 0, stream>>>(x, xh, BATCH * T_SEQ * DMODEL / 8);
  k_transpose_f16<<<dim3(4096 / 32, 2048 / 32), 256, 0, stream>>>(Wq, WqkvT, DMODEL, 4096);
  k_transpose_f16<<<dim3(2048 / 32, 2048 / 32), 256, 0, stream>>>(Wk, WqkvT + (size_t)4096 * 2048, DMODEL, 2048);
  k_transpose_f16<<<dim3(2048 / 32, 2048 / 32), 256, 0, stream>>>(Wv, WqkvT + (size_t)6144 * 2048, DMODEL, 2048);
  k_transpose_f16<<<dim3(2048 / 32, 2048 / 32), 256, 0, stream>>>(Wo, WoT, 2048, 2048);
  k_lambda<<<4096, 256, 0, stream>>>(x, Wlam, lam);

  // fused QKV projection + RoPE + V-transpose: M=4096, N=8192, K=2048
  k_gemm2<256, 256, 2, 4, 3><<<512, 512, 0, stream>>>(xh, WqkvT, Qh, Kh, VTg,
                                                      cosb, sinb, 4096, 8192, 2048);

  k_attn4<<<1024, 256, 0, stream>>>(Qh, Kh, VTg, At);

  k_combine<<<(BATCH * T_SEQ * 16 * 32) / 256, 256, 0, stream>>>(At, lam, Zh);

  // output projection: M=4096, N=2048, K=2048 -> f32 d_out
  k_gemm2<256, 128, 4, 2, 0><<<256, 512, 0, stream>>>(Zh, WoT, d_out, nullptr, nullptr,
                                                      nullptr, nullptr, 4096, 2048, 2048);
}